// Round 6
// baseline (251.996 us; speedup 1.0000x reference)
//
#include <hip/hip_runtime.h>
#include <math.h>

#define NN 512
#define CSd 384
#define CATd 2112
#define KF_CHUNK 264
#define KF_SPLIT 8

// padded logits-tile index: 12 rows, each row = 8 sub-blocks of 64 j padded to 68
__device__ __forceinline__ int aidx(int h, int j) {
  return h * 544 + ((j >> 6) * 68) + (j & 63);
}
__device__ __forceinline__ float f4c(const float4& v, int k) {
  return k == 0 ? v.x : (k == 1 ? v.y : (k == 2 ? v.z : v.w));
}

// ---------------- Kernel 1a: fused projection GEMM ----------------
__global__ void k_projgemm(const float* __restrict__ s,
                           const float* __restrict__ w_q, const float* __restrict__ b_q,
                           const float* __restrict__ w_kv, const float* __restrict__ b_kv,
                           const float* __restrict__ w_qp, const float* __restrict__ b_qp,
                           const float* __restrict__ w_kvp, const float* __restrict__ b_kvp,
                           float* __restrict__ proj)
{
  __shared__ float sT[384 * 40];
  const int t  = threadIdx.x;
  const int i0 = blockIdx.x * 32;
  const int c0 = blockIdx.y * 64;

  for (int u = t; u < 32 * 384; u += 256) {
    int row = u / 384, col = u % 384;
    sT[col * 40 + row] = s[(i0 + row) * CSd + col];
  }
  __syncthreads();

  const int c    = t & 63;
  const int rgrp = t >> 6;
  const int gc   = c0 + c;

  const float* wp;
  int stride;
  float bias;
  if (gc < 192)      { wp = w_q   + gc;         stride = 192; bias = b_q[gc]; }
  else if (gc < 576) { wp = w_kv  + (gc - 192); stride = 384; bias = b_kv[gc - 192]; }
  else if (gc < 720) { wp = w_qp  + (gc - 576); stride = 144; bias = b_qp[gc - 576]; }
  else               { wp = w_kvp + (gc - 720); stride = 432; bias = b_kvp[gc - 720]; }

  float acc[8];
#pragma unroll
  for (int j = 0; j < 8; j++) acc[j] = bias;

  const int r0 = rgrp * 8;
#pragma unroll 4
  for (int kk = 0; kk < 384; kk++) {
    float wv = *wp; wp += stride;
    const float4 a0 = *reinterpret_cast<const float4*>(&sT[kk * 40 + r0]);
    const float4 a1 = *reinterpret_cast<const float4*>(&sT[kk * 40 + r0 + 4]);
    acc[0] += a0.x * wv; acc[1] += a0.y * wv; acc[2] += a0.z * wv; acc[3] += a0.w * wv;
    acc[4] += a1.x * wv; acc[5] += a1.y * wv; acc[6] += a1.z * wv; acc[7] += a1.w * wv;
  }
#pragma unroll
  for (int j = 0; j < 8; j++)
    proj[(size_t)(i0 + r0 + j) * 1152 + gc] = acc[j];
}

// ---------------- Kernel 1b: scatter q/kT/vcat + rotate points ----------------
__global__ void k_rot(const float* __restrict__ proj,
                      const float* __restrict__ rot, const float* __restrict__ trans,
                      float* __restrict__ q, float* __restrict__ kT, float* __restrict__ vcat,
                      float* __restrict__ qp, float* __restrict__ kpT)
{
  __shared__ float ptsL[576];
  const int i = blockIdx.x, t = threadIdx.x;
  const float* pr = proj + (size_t)i * 1152;

  for (int u = t; u < 576; u += 256) ptsL[u] = pr[576 + u];

  for (int cI = t; cI < 576; cI += 256) {
    float pv = pr[cI];
    if (cI < 192) q[i * 192 + cI] = pv;
    else {
      int local = cI - 192, h = local >> 5, cc = local & 31;
      if (cc < 16) kT[(size_t)(h * 16 + cc) * NN + i] = pv;
      else         vcat[(size_t)i * 480 + h * 16 + (cc - 16)] = pv;
    }
  }
  __syncthreads();

  for (int p = t; p < 192; p += 256) {
    float x, y, zz;
    if (p < 48) { x = ptsL[p]; y = ptsL[48 + p]; zz = ptsL[96 + p]; }
    else { int idx = p - 48; x = ptsL[144 + idx]; y = ptsL[288 + idx]; zz = ptsL[432 + idx]; }
    const float* Rm = rot + i * 9;
    const float* tr = trans + i * 3;
    float rx = Rm[0] * x + Rm[1] * y + Rm[2] * zz + tr[0];
    float ry = Rm[3] * x + Rm[4] * y + Rm[5] * zz + tr[1];
    float rz = Rm[6] * x + Rm[7] * y + Rm[8] * zz + tr[2];
    if (p < 48) {
      float* d = qp + ((size_t)i * 48 + p) * 3;
      d[0] = rx; d[1] = ry; d[2] = rz;
    } else {
      int idx = p - 48, h = idx / 12, pp = idx % 12;
      if (pp < 4) {
        size_t rbase = (size_t)((h * 4 + pp) * 3) * NN + i;
        kpT[rbase] = rx; kpT[rbase + NN] = ry; kpT[rbase + 2 * NN] = rz;
      } else {
        size_t rbase = (size_t)i * 480 + 192 + (h * 8 + pp - 4) * 3;
        vcat[rbase] = rx; vcat[rbase + 1] = ry; vcat[rbase + 2] = rz;
      }
    }
  }
}

// ---------------- Kernel 2: full logits = z@w_b + qk + pt + mask ----------------
// grid 4096 (i, 64-j slice), 256 threads
__global__ void k_bias(const float* __restrict__ z, const float* __restrict__ w_b,
                       const float* __restrict__ b_b, const float* __restrict__ mask,
                       const float* __restrict__ q, const float* __restrict__ kT,
                       const float* __restrict__ qp, const float* __restrict__ kpT,
                       const float* __restrict__ hws,
                       float* __restrict__ a)
{
  __shared__ float zL[64 * 132];
  __shared__ float wT[12 * 128];
  __shared__ float red[4][64][13];
  __shared__ float qL[192], qpL[144], hwL[12];
  const int t = threadIdx.x;
  const int row0 = blockIdx.x * 64;
  const int i = row0 >> 9;
  const int j0 = row0 & 511;

  for (int u = t; u < 1536; u += 256) {
    int h = u >> 7, c = u & 127;
    wT[u] = w_b[c * 12 + h];
  }
  const float4* z4 = reinterpret_cast<const float4*>(z + (size_t)row0 * 128);
  for (int u = t; u < 64 * 32; u += 256) {
    int r = u >> 5, c4 = u & 31;
    *reinterpret_cast<float4*>(&zL[r * 132 + c4 * 4]) = z4[u];
  }
  for (int u = t; u < 192; u += 256) qL[u] = q[i * 192 + u];
  for (int u = t; u < 144; u += 256) qpL[u] = qp[(size_t)i * 144 + u];
  for (int u = t; u < 12; u += 256) hwL[u] = 0.13608276348f * log1pf(expf(hws[u]));
  __syncthreads();

  {
    const int r = t & 63, cq = t >> 6;
    float4 zr[8];
#pragma unroll
    for (int i4 = 0; i4 < 8; i4++)
      zr[i4] = *reinterpret_cast<const float4*>(&zL[r * 132 + cq * 32 + i4 * 4]);
#pragma unroll
    for (int h = 0; h < 12; h++) {
      float sv = 0.f;
#pragma unroll
      for (int i4 = 0; i4 < 8; i4++) {
        const float4 w = *reinterpret_cast<const float4*>(&wT[h * 128 + cq * 32 + i4 * 4]);
        sv += zr[i4].x * w.x + zr[i4].y * w.y + zr[i4].z * w.z + zr[i4].w * w.w;
      }
      red[cq][r][h] = sv;
    }
  }
  __syncthreads();

  const int r = t & 63, hg = t >> 6;
  const float mi = mask[i], mj = mask[j0 + r];
  const float mterm = 100000.0f * (mi * mj - 1.0f);
  const float W_L = 0.57735026919f;
  const float W_C = 0.14433756730f;
  for (int h = hg * 3; h < hg * 3 + 3; h++) {
    float sv = b_b[h] + red[0][r][h] + red[1][r][h] + red[2][r][h] + red[3][r][h];
    float dot = 0.f;
#pragma unroll
    for (int c = 0; c < 16; c++)
      dot += qL[h * 16 + c] * kT[(size_t)(h * 16 + c) * NN + j0 + r];
    float d2 = 0.f;
#pragma unroll
    for (int pc = 0; pc < 12; pc++) {
      float kv = kpT[(size_t)(h * 12 + pc) * NN + j0 + r];
      float dd = qpL[h * 12 + pc] - kv;
      d2 += dd * dd;
    }
    a[((size_t)h * NN + i) * NN + j0 + r] = W_L * sv + mterm + W_C * dot - 0.5f * hwL[h] * d2;
  }
}

// ---------------- Kernel 3: softmax + o + o_pt + o_pair (register-tiled) ----------------
// grid 512 (one per i), 512 threads
__global__ void __launch_bounds__(512, 2)
k_out(const float* __restrict__ a, const float* __restrict__ vcat,
      const float* __restrict__ z,
      const float* __restrict__ rot, const float* __restrict__ trans,
      float* __restrict__ cat)
{
  __shared__ float aL[12 * 544];      // 26.1 KB, padded layout via aidx()
  __shared__ float redp[8][16][56];   // 28.7 KB, GEMM-1 wave partials (h-halves)
  __shared__ float optF[288];
  float* red2 = &redp[0][0][0];       // GEMM-2 reuse: [8][64][8] = 4096 floats

  const int i = blockIdx.x, t = threadIdx.x;

  // ---- stage logits tile ----
  for (int u = t; u < 12 * 512; u += 512) {
    int h = u >> 9, j = u & 511;
    aL[aidx(h, j)] = a[((size_t)h * NN + i) * NN + j];
  }
  __syncthreads();

  // ---- softmax in LDS: wave w handles rows h = w (+8) ----
  {
    const int wv = t >> 6, l = t & 63;
    for (int h = wv; h < 12; h += 8) {
      const int j0 = l * 8;
      float4 x0 = *reinterpret_cast<const float4*>(&aL[aidx(h, j0)]);
      float4 x1 = *reinterpret_cast<const float4*>(&aL[aidx(h, j0 + 4)]);
      float m8 = fmaxf(fmaxf(fmaxf(x0.x, x0.y), fmaxf(x0.z, x0.w)),
                       fmaxf(fmaxf(x1.x, x1.y), fmaxf(x1.z, x1.w)));
      for (int o = 1; o < 64; o <<= 1) m8 = fmaxf(m8, __shfl_xor(m8, o));
      x0.x = expf(x0.x - m8); x0.y = expf(x0.y - m8);
      x0.z = expf(x0.z - m8); x0.w = expf(x0.w - m8);
      x1.x = expf(x1.x - m8); x1.y = expf(x1.y - m8);
      x1.z = expf(x1.z - m8); x1.w = expf(x1.w - m8);
      float s8 = x0.x + x0.y + x0.z + x0.w + x1.x + x1.y + x1.z + x1.w;
      for (int o = 1; o < 64; o <<= 1) s8 += __shfl_xor(s8, o);
      float inv = 1.0f / s8;
      x0.x *= inv; x0.y *= inv; x0.z *= inv; x0.w *= inv;
      x1.x *= inv; x1.y *= inv; x1.z *= inv; x1.w *= inv;
      *reinterpret_cast<float4*>(&aL[aidx(h, j0)]) = x0;
      *reinterpret_cast<float4*>(&aL[aidx(h, j0 + 4)]) = x1;
    }
  }
  __syncthreads();

  // ---- GEMM-1: o_pair[12][128] = P @ z[i] ----
  const int cg = t & 15;            // c-group (8 cols)
  const int jq = (t >> 4) & 3;      // within-wave j sub-slice
  const int wv = t >> 6;            // wave = 64-j slice
  float acc1[12][8];
#pragma unroll
  for (int h = 0; h < 12; h++)
#pragma unroll
    for (int c = 0; c < 8; c++) acc1[h][c] = 0.f;

  {
    const int c8 = cg * 8;
    const int jb = wv * 64 + jq * 16;
    const float* zb = z + (size_t)i * 65536 + c8;
    for (int ch = 0; ch < 4; ch++) {
      const int j0c = jb + ch * 4;
      float4 p4[12];
#pragma unroll
      for (int h = 0; h < 12; h++)
        p4[h] = *reinterpret_cast<const float4*>(&aL[aidx(h, j0c)]);
#pragma unroll
      for (int jj = 0; jj < 4; jj++) {
        const float4 za = *reinterpret_cast<const float4*>(&zb[(size_t)(j0c + jj) * 128]);
        const float4 zc = *reinterpret_cast<const float4*>(&zb[(size_t)(j0c + jj) * 128 + 4]);
#pragma unroll
        for (int h = 0; h < 12; h++) {
          const float pv = f4c(p4[h], jj);
          acc1[h][0] += pv * za.x; acc1[h][1] += pv * za.y;
          acc1[h][2] += pv * za.z; acc1[h][3] += pv * za.w;
          acc1[h][4] += pv * zc.x; acc1[h][5] += pv * zc.y;
          acc1[h][6] += pv * zc.z; acc1[h][7] += pv * zc.w;
        }
      }
    }
    // reduce the 4 jq sub-slices (lane bits 4,5)
#pragma unroll
    for (int h = 0; h < 12; h++)
#pragma unroll
      for (int c = 0; c < 8; c++) {
        float v2 = acc1[h][c];
        v2 += __shfl_xor(v2, 16);
        v2 += __shfl_xor(v2, 32);
        acc1[h][c] = v2;
      }
  }

  // ---- h-half A (0..5): write partials, sum, store ----
  if (jq == 0) {
#pragma unroll
    for (int h = 0; h < 6; h++) {
      *reinterpret_cast<float4*>(&redp[wv][cg][h * 8]) =
        make_float4(acc1[h][0], acc1[h][1], acc1[h][2], acc1[h][3]);
      *reinterpret_cast<float4*>(&redp[wv][cg][h * 8 + 4]) =
        make_float4(acc1[h][4], acc1[h][5], acc1[h][6], acc1[h][7]);
    }
  }
  __syncthreads();
  for (int e = t; e < 768; e += 512) {
    int h = e >> 7, c = e & 127;
    float sv = 0.f;
#pragma unroll
    for (int w2 = 0; w2 < 8; w2++) sv += redp[w2][c >> 3][h * 8 + (c & 7)];
    cat[(size_t)i * CATd + 576 + e] = sv;
  }
  __syncthreads();

  // ---- h-half B (6..11) ----
  if (jq == 0) {
#pragma unroll
    for (int h = 0; h < 6; h++) {
      *reinterpret_cast<float4*>(&redp[wv][cg][h * 8]) =
        make_float4(acc1[6 + h][0], acc1[6 + h][1], acc1[6 + h][2], acc1[6 + h][3]);
      *reinterpret_cast<float4*>(&redp[wv][cg][h * 8 + 4]) =
        make_float4(acc1[6 + h][4], acc1[6 + h][5], acc1[6 + h][6], acc1[6 + h][7]);
    }
  }
  __syncthreads();
  for (int e = t; e < 768; e += 512) {
    int h = e >> 7, c = e & 127;
    float sv = 0.f;
#pragma unroll
    for (int w2 = 0; w2 < 8; w2++) sv += redp[w2][c >> 3][h * 8 + (c & 7)];
    cat[(size_t)i * CATd + 576 + 768 + e] = sv;
  }
  __syncthreads();

  // ---- GEMM-2: o[h][16] and o_pt[h][24] (block-diagonal, one h per thread) ----
  const int oc = t & 63, jw = t >> 6;
  const int h2 = oc / 5, c5 = oc - h2 * 5;
  const int c8b = c5 * 8;
  float acc2[8];
#pragma unroll
  for (int c = 0; c < 8; c++) acc2[c] = 0.f;

  if (oc < 60) {
    const int vbase = (c8b < 16) ? (h2 * 16 + c8b) : (192 + h2 * 24 + (c8b - 16));
    for (int ch = 0; ch < 16; ch++) {
      const int j0c = jw * 64 + ch * 4;
      const float4 p4 = *reinterpret_cast<const float4*>(&aL[aidx(h2, j0c)]);
#pragma unroll
      for (int jj = 0; jj < 4; jj++) {
        const float* vr = &vcat[(size_t)(j0c + jj) * 480 + vbase];
        const float4 va = *reinterpret_cast<const float4*>(vr);
        const float4 vb = *reinterpret_cast<const float4*>(vr + 4);
        const float pv = f4c(p4, jj);
        acc2[0] += pv * va.x; acc2[1] += pv * va.y;
        acc2[2] += pv * va.z; acc2[3] += pv * va.w;
        acc2[4] += pv * vb.x; acc2[5] += pv * vb.y;
        acc2[6] += pv * vb.z; acc2[7] += pv * vb.w;
      }
    }
  }
  if (oc < 60) {
    *reinterpret_cast<float4*>(&red2[((size_t)jw * 64 + oc) * 8]) =
      make_float4(acc2[0], acc2[1], acc2[2], acc2[3]);
    *reinterpret_cast<float4*>(&red2[((size_t)jw * 64 + oc) * 8 + 4]) =
      make_float4(acc2[4], acc2[5], acc2[6], acc2[7]);
  }
  __syncthreads();

  for (int e = t; e < 480; e += 512) {
    const int oc2 = e >> 3, cc = e & 7;
    float sv = 0.f;
#pragma unroll
    for (int w2 = 0; w2 < 8; w2++) sv += red2[((size_t)w2 * 64 + oc2) * 8 + cc];
    const int hh = e / 40, c40 = e - hh * 40;
    if (c40 < 16) cat[(size_t)i * CATd + hh * 16 + c40] = sv;
    else optF[hh * 24 + (c40 - 16)] = sv;
  }
  __syncthreads();

  // ---- inverse rotation + norm ----
  if (t < 96) {
    const int h = t >> 3, p = t & 7;
    const float* Rm = rot + i * 9;
    const float* tr = trans + i * 3;
    float ox = optF[h * 24 + p * 3 + 0] - tr[0];
    float oy = optF[h * 24 + p * 3 + 1] - tr[1];
    float oz = optF[h * 24 + p * 3 + 2] - tr[2];
    float rx = Rm[0] * ox + Rm[3] * oy + Rm[6] * oz;
    float ry = Rm[1] * ox + Rm[4] * oy + Rm[7] * oz;
    float rz = Rm[2] * ox + Rm[5] * oy + Rm[8] * oz;
    float nrm = sqrtf(rx * rx + ry * ry + rz * rz + 1e-8f);
    size_t b = (size_t)i * CATd;
    cat[b + 192 + t] = rx; cat[b + 288 + t] = ry;
    cat[b + 384 + t] = rz; cat[b + 480 + t] = nrm;
  }
}

// ---------------- Kernel 5: split-K GEMM out = cat @ w_out ----------------
__global__ void k_final(const float* __restrict__ cat, const float* __restrict__ w_out,
                        float* __restrict__ part)
{
  __shared__ float sT[KF_CHUNK * 36];
  const int t  = threadIdx.x;
  const int i0 = blockIdx.x * 32;
  const int c0 = blockIdx.y * 64;
  const int k0 = blockIdx.z * KF_CHUNK;

  for (int u = t; u < 32 * KF_CHUNK; u += 256) {
    int row = u / KF_CHUNK, kk = u % KF_CHUNK;
    sT[kk * 36 + row] = cat[(size_t)(i0 + row) * CATd + k0 + kk];
  }
  __syncthreads();

  const int c    = t & 63;
  const int rgrp = t >> 6;
  const int r0   = rgrp * 8;
  const int gc   = c0 + c;

  float acc[8];
#pragma unroll
  for (int j = 0; j < 8; j++) acc[j] = 0.f;

  const float* wp = w_out + (size_t)k0 * 384 + gc;
#pragma unroll 4
  for (int kk = 0; kk < KF_CHUNK; kk++) {
    float wv = wp[(size_t)kk * 384];
    const float4 a0 = *reinterpret_cast<const float4*>(&sT[kk * 36 + r0]);
    const float4 a1 = *reinterpret_cast<const float4*>(&sT[kk * 36 + r0 + 4]);
    acc[0] += a0.x * wv; acc[1] += a0.y * wv; acc[2] += a0.z * wv; acc[3] += a0.w * wv;
    acc[4] += a1.x * wv; acc[5] += a1.y * wv; acc[6] += a1.z * wv; acc[7] += a1.w * wv;
  }

  float* pb = part + (size_t)blockIdx.z * NN * 384;
#pragma unroll
  for (int j = 0; j < 8; j++)
    pb[(size_t)(i0 + r0 + j) * 384 + gc] = acc[j];
}

// ---------------- Kernel 6: reduce partials + bias ----------------
__global__ void k_reduce(const float* __restrict__ part, const float* __restrict__ b_out,
                         float* __restrict__ out)
{
  const int idx = blockIdx.x * 256 + threadIdx.x;
  const int c = idx % 384;
  float acc = b_out[c];
#pragma unroll
  for (int ks = 0; ks < KF_SPLIT; ks++)
    acc += part[(size_t)ks * NN * 384 + idx];
  out[idx] = acc;
}

extern "C" void kernel_launch(void* const* d_in, const int* in_sizes, int n_in,
                              void* d_out, int out_size, void* d_ws, size_t ws_size,
                              hipStream_t stream) {
  const float* s      = (const float*)d_in[0];
  const float* z      = (const float*)d_in[1];
  const float* rot    = (const float*)d_in[2];
  const float* trans  = (const float*)d_in[3];
  const float* mask   = (const float*)d_in[4];
  const float* w_q    = (const float*)d_in[5];
  const float* b_q    = (const float*)d_in[6];
  const float* w_kv   = (const float*)d_in[7];
  const float* b_kv   = (const float*)d_in[8];
  const float* w_qp   = (const float*)d_in[9];
  const float* b_qp   = (const float*)d_in[10];
  const float* w_kvp  = (const float*)d_in[11];
  const float* b_kvp  = (const float*)d_in[12];
  const float* w_b    = (const float*)d_in[13];
  const float* b_b    = (const float*)d_in[14];
  const float* hws    = (const float*)d_in[15];
  const float* w_out  = (const float*)d_in[16];
  const float* b_out  = (const float*)d_in[17];
  float* out = (float*)d_out;

  float* ws   = (float*)d_ws;
  float* q    = ws;                  // 512*192
  float* kT   = q    + 98304;        // [192][512] j-major
  float* vcat = kT   + 98304;        // [512][480] = [v | vp_rot]
  float* qp   = vcat + 245760;       // 512*144
  float* kpT  = qp   + 73728;        // [144][512] j-major
  float* a    = kpT  + 73728;        // 12*512*512 logits
  float* cat  = a    + 3145728;      // 512*2112
  float* proj = a;                   // alias: consumed before k_bias writes a
  float* part = a;                   // alias: logits dead after k_out

  k_projgemm<<<dim3(16, 18), 256, 0, stream>>>(s, w_q, b_q, w_kv, b_kv,
                                               w_qp, b_qp, w_kvp, b_kvp, proj);
  k_rot<<<512, 256, 0, stream>>>(proj, rot, trans, q, kT, vcat, qp, kpT);
  k_bias<<<4096, 256, 0, stream>>>(z, w_b, b_b, mask, q, kT, qp, kpT, hws, a);
  k_out<<<512, 512, 0, stream>>>(a, vcat, z, rot, trans, cat);
  k_final<<<dim3(16, 6, KF_SPLIT), 256, 0, stream>>>(cat, w_out, part);
  k_reduce<<<768, 256, 0, stream>>>(part, b_out, out);
}

// Round 7
// 201.488 us; speedup vs baseline: 1.2507x; 1.2507x over previous
//
#include <hip/hip_runtime.h>
#include <math.h>

#define NN 512
#define CSd 384
#define CATd 2112
#define KF_CHUNK 264
#define KF_SPLIT 8

// padded logits-tile index: 12 rows, each row = 8 sub-blocks of 64 j padded to 68
__device__ __forceinline__ int aidx(int h, int j) {
  return h * 544 + ((j >> 6) * 68) + (j & 63);
}
__device__ __forceinline__ float f4c(const float4& v, int k) {
  return k == 0 ? v.x : (k == 1 ? v.y : (k == 2 ? v.z : v.w));
}

// ---------------- Kernel 1a: fused projection GEMM ----------------
__global__ void k_projgemm(const float* __restrict__ s,
                           const float* __restrict__ w_q, const float* __restrict__ b_q,
                           const float* __restrict__ w_kv, const float* __restrict__ b_kv,
                           const float* __restrict__ w_qp, const float* __restrict__ b_qp,
                           const float* __restrict__ w_kvp, const float* __restrict__ b_kvp,
                           float* __restrict__ proj)
{
  __shared__ float sT[384 * 40];
  const int t  = threadIdx.x;
  const int i0 = blockIdx.x * 32;
  const int c0 = blockIdx.y * 64;

  for (int u = t; u < 32 * 384; u += 256) {
    int row = u / 384, col = u % 384;
    sT[col * 40 + row] = s[(i0 + row) * CSd + col];
  }
  __syncthreads();

  const int c    = t & 63;
  const int rgrp = t >> 6;
  const int gc   = c0 + c;

  const float* wp;
  int stride;
  float bias;
  if (gc < 192)      { wp = w_q   + gc;         stride = 192; bias = b_q[gc]; }
  else if (gc < 576) { wp = w_kv  + (gc - 192); stride = 384; bias = b_kv[gc - 192]; }
  else if (gc < 720) { wp = w_qp  + (gc - 576); stride = 144; bias = b_qp[gc - 576]; }
  else               { wp = w_kvp + (gc - 720); stride = 432; bias = b_kvp[gc - 720]; }

  float acc[8];
#pragma unroll
  for (int j = 0; j < 8; j++) acc[j] = bias;

  const int r0 = rgrp * 8;
#pragma unroll 4
  for (int kk = 0; kk < 384; kk++) {
    float wv = *wp; wp += stride;
    const float4 a0 = *reinterpret_cast<const float4*>(&sT[kk * 40 + r0]);
    const float4 a1 = *reinterpret_cast<const float4*>(&sT[kk * 40 + r0 + 4]);
    acc[0] += a0.x * wv; acc[1] += a0.y * wv; acc[2] += a0.z * wv; acc[3] += a0.w * wv;
    acc[4] += a1.x * wv; acc[5] += a1.y * wv; acc[6] += a1.z * wv; acc[7] += a1.w * wv;
  }
#pragma unroll
  for (int j = 0; j < 8; j++)
    proj[(size_t)(i0 + r0 + j) * 1152 + gc] = acc[j];
}

// ---------------- Kernel 1b: scatter q/kT/vcat + rotate points ----------------
__global__ void k_rot(const float* __restrict__ proj,
                      const float* __restrict__ rot, const float* __restrict__ trans,
                      float* __restrict__ q, float* __restrict__ kT, float* __restrict__ vcat,
                      float* __restrict__ qp, float* __restrict__ kpT)
{
  __shared__ float ptsL[576];
  const int i = blockIdx.x, t = threadIdx.x;
  const float* pr = proj + (size_t)i * 1152;

  for (int u = t; u < 576; u += 256) ptsL[u] = pr[576 + u];

  for (int cI = t; cI < 576; cI += 256) {
    float pv = pr[cI];
    if (cI < 192) q[i * 192 + cI] = pv;
    else {
      int local = cI - 192, h = local >> 5, cc = local & 31;
      if (cc < 16) kT[(size_t)(h * 16 + cc) * NN + i] = pv;
      else         vcat[(size_t)i * 480 + h * 16 + (cc - 16)] = pv;
    }
  }
  __syncthreads();

  for (int p = t; p < 192; p += 256) {
    float x, y, zz;
    if (p < 48) { x = ptsL[p]; y = ptsL[48 + p]; zz = ptsL[96 + p]; }
    else { int idx = p - 48; x = ptsL[144 + idx]; y = ptsL[288 + idx]; zz = ptsL[432 + idx]; }
    const float* Rm = rot + i * 9;
    const float* tr = trans + i * 3;
    float rx = Rm[0] * x + Rm[1] * y + Rm[2] * zz + tr[0];
    float ry = Rm[3] * x + Rm[4] * y + Rm[5] * zz + tr[1];
    float rz = Rm[6] * x + Rm[7] * y + Rm[8] * zz + tr[2];
    if (p < 48) {
      float* d = qp + ((size_t)i * 48 + p) * 3;
      d[0] = rx; d[1] = ry; d[2] = rz;
    } else {
      int idx = p - 48, h = idx / 12, pp = idx % 12;
      if (pp < 4) {
        size_t rbase = (size_t)((h * 4 + pp) * 3) * NN + i;
        kpT[rbase] = rx; kpT[rbase + NN] = ry; kpT[rbase + 2 * NN] = rz;
      } else {
        size_t rbase = (size_t)i * 480 + 192 + (h * 8 + pp - 4) * 3;
        vcat[rbase] = rx; vcat[rbase + 1] = ry; vcat[rbase + 2] = rz;
      }
    }
  }
}

// ---------------- Kernel 2: logits = z@w_b + qk + pt + mask (reg-direct) ----------------
// grid 1024 (i = b>>1, j-half = b&1), 256 threads; thread owns one (i,j); no LDS.
__global__ void k_logits(const float* __restrict__ z, const float* __restrict__ w_b,
                         const float* __restrict__ b_b, const float* __restrict__ mask,
                         const float* __restrict__ q, const float* __restrict__ kT,
                         const float* __restrict__ qp, const float* __restrict__ kpT,
                         const float* __restrict__ hws,
                         float* __restrict__ a)
{
  const int t = threadIdx.x;
  const int i = blockIdx.x >> 1;
  const int j = ((blockIdx.x & 1) << 8) + t;

  // ---- z @ w_b: stream 128 c in 4 chunks of 8 float4 ----
  float acc[12];
#pragma unroll
  for (int h = 0; h < 12; h++) acc[h] = 0.f;

  const float4* zr = reinterpret_cast<const float4*>(z + ((size_t)i * NN + j) * 128);
#pragma unroll
  for (int ch = 0; ch < 4; ch++) {
    float4 zc[8];
#pragma unroll
    for (int u = 0; u < 8; u++) zc[u] = zr[ch * 8 + u];
#pragma unroll
    for (int u = 0; u < 8; u++) {
      const int c0 = ch * 32 + u * 4;
#pragma unroll
      for (int h = 0; h < 12; h++) {
        // w_b row-major [128][12]; i-uniform-free: these are lane-uniform scalar loads
        acc[h] += zc[u].x * w_b[(c0 + 0) * 12 + h]
                + zc[u].y * w_b[(c0 + 1) * 12 + h]
                + zc[u].z * w_b[(c0 + 2) * 12 + h]
                + zc[u].w * w_b[(c0 + 3) * 12 + h];
      }
    }
  }

  const float mterm = 100000.0f * (mask[i] * mask[j] - 1.0f);
  const float W_L = 0.57735026919f;
  const float W_C = 0.14433756730f;

  // ---- qk + point term, per h; q/qp are block-uniform (scalar-loaded) ----
#pragma unroll
  for (int h = 0; h < 12; h++) {
    float dot = 0.f;
#pragma unroll
    for (int c = 0; c < 16; c++)
      dot += q[i * 192 + h * 16 + c] * kT[(size_t)(h * 16 + c) * NN + j];
    float d2 = 0.f;
#pragma unroll
    for (int pc = 0; pc < 12; pc++) {
      float dd = qp[(size_t)i * 144 + h * 12 + pc] - kpT[(size_t)(h * 12 + pc) * NN + j];
      d2 += dd * dd;
    }
    const float hwv = 0.13608276348f * log1pf(expf(hws[h]));
    a[((size_t)h * NN + i) * NN + j] =
        W_L * (acc[h] + b_b[h]) + mterm + W_C * dot - 0.5f * hwv * d2;
  }
}

// ---------------- Kernel 3: softmax + o + o_pt + o_pair (register-tiled) ----------------
// grid 512 (one per i), 512 threads
__global__ void __launch_bounds__(512, 2)
k_out(const float* __restrict__ a, const float* __restrict__ vcat,
      const float* __restrict__ z,
      const float* __restrict__ rot, const float* __restrict__ trans,
      float* __restrict__ cat)
{
  __shared__ float aL[12 * 544];
  __shared__ float redp[8][16][56];
  __shared__ float optF[288];
  float* red2 = &redp[0][0][0];

  const int i = blockIdx.x, t = threadIdx.x;

  for (int u = t; u < 12 * 512; u += 512) {
    int h = u >> 9, j = u & 511;
    aL[aidx(h, j)] = a[((size_t)h * NN + i) * NN + j];
  }
  __syncthreads();

  {
    const int wv = t >> 6, l = t & 63;
    for (int h = wv; h < 12; h += 8) {
      const int j0 = l * 8;
      float4 x0 = *reinterpret_cast<const float4*>(&aL[aidx(h, j0)]);
      float4 x1 = *reinterpret_cast<const float4*>(&aL[aidx(h, j0 + 4)]);
      float m8 = fmaxf(fmaxf(fmaxf(x0.x, x0.y), fmaxf(x0.z, x0.w)),
                       fmaxf(fmaxf(x1.x, x1.y), fmaxf(x1.z, x1.w)));
      for (int o = 1; o < 64; o <<= 1) m8 = fmaxf(m8, __shfl_xor(m8, o));
      x0.x = expf(x0.x - m8); x0.y = expf(x0.y - m8);
      x0.z = expf(x0.z - m8); x0.w = expf(x0.w - m8);
      x1.x = expf(x1.x - m8); x1.y = expf(x1.y - m8);
      x1.z = expf(x1.z - m8); x1.w = expf(x1.w - m8);
      float s8 = x0.x + x0.y + x0.z + x0.w + x1.x + x1.y + x1.z + x1.w;
      for (int o = 1; o < 64; o <<= 1) s8 += __shfl_xor(s8, o);
      float inv = 1.0f / s8;
      x0.x *= inv; x0.y *= inv; x0.z *= inv; x0.w *= inv;
      x1.x *= inv; x1.y *= inv; x1.z *= inv; x1.w *= inv;
      *reinterpret_cast<float4*>(&aL[aidx(h, j0)]) = x0;
      *reinterpret_cast<float4*>(&aL[aidx(h, j0 + 4)]) = x1;
    }
  }
  __syncthreads();

  const int cg = t & 15;
  const int jq = (t >> 4) & 3;
  const int wv = t >> 6;
  float acc1[12][8];
#pragma unroll
  for (int h = 0; h < 12; h++)
#pragma unroll
    for (int c = 0; c < 8; c++) acc1[h][c] = 0.f;

  {
    const int c8 = cg * 8;
    const int jb = wv * 64 + jq * 16;
    const float* zb = z + (size_t)i * 65536 + c8;
    for (int ch = 0; ch < 4; ch++) {
      const int j0c = jb + ch * 4;
      float4 p4[12];
#pragma unroll
      for (int h = 0; h < 12; h++)
        p4[h] = *reinterpret_cast<const float4*>(&aL[aidx(h, j0c)]);
#pragma unroll
      for (int jj = 0; jj < 4; jj++) {
        const float4 za = *reinterpret_cast<const float4*>(&zb[(size_t)(j0c + jj) * 128]);
        const float4 zc = *reinterpret_cast<const float4*>(&zb[(size_t)(j0c + jj) * 128 + 4]);
#pragma unroll
        for (int h = 0; h < 12; h++) {
          const float pv = f4c(p4[h], jj);
          acc1[h][0] += pv * za.x; acc1[h][1] += pv * za.y;
          acc1[h][2] += pv * za.z; acc1[h][3] += pv * za.w;
          acc1[h][4] += pv * zc.x; acc1[h][5] += pv * zc.y;
          acc1[h][6] += pv * zc.z; acc1[h][7] += pv * zc.w;
        }
      }
    }
#pragma unroll
    for (int h = 0; h < 12; h++)
#pragma unroll
      for (int c = 0; c < 8; c++) {
        float v2 = acc1[h][c];
        v2 += __shfl_xor(v2, 16);
        v2 += __shfl_xor(v2, 32);
        acc1[h][c] = v2;
      }
  }

  if (jq == 0) {
#pragma unroll
    for (int h = 0; h < 6; h++) {
      *reinterpret_cast<float4*>(&redp[wv][cg][h * 8]) =
        make_float4(acc1[h][0], acc1[h][1], acc1[h][2], acc1[h][3]);
      *reinterpret_cast<float4*>(&redp[wv][cg][h * 8 + 4]) =
        make_float4(acc1[h][4], acc1[h][5], acc1[h][6], acc1[h][7]);
    }
  }
  __syncthreads();
  for (int e = t; e < 768; e += 512) {
    int h = e >> 7, c = e & 127;
    float sv = 0.f;
#pragma unroll
    for (int w2 = 0; w2 < 8; w2++) sv += redp[w2][c >> 3][h * 8 + (c & 7)];
    cat[(size_t)i * CATd + 576 + e] = sv;
  }
  __syncthreads();

  if (jq == 0) {
#pragma unroll
    for (int h = 0; h < 6; h++) {
      *reinterpret_cast<float4*>(&redp[wv][cg][h * 8]) =
        make_float4(acc1[6 + h][0], acc1[6 + h][1], acc1[6 + h][2], acc1[6 + h][3]);
      *reinterpret_cast<float4*>(&redp[wv][cg][h * 8 + 4]) =
        make_float4(acc1[6 + h][4], acc1[6 + h][5], acc1[6 + h][6], acc1[6 + h][7]);
    }
  }
  __syncthreads();
  for (int e = t; e < 768; e += 512) {
    int h = e >> 7, c = e & 127;
    float sv = 0.f;
#pragma unroll
    for (int w2 = 0; w2 < 8; w2++) sv += redp[w2][c >> 3][h * 8 + (c & 7)];
    cat[(size_t)i * CATd + 576 + 768 + e] = sv;
  }
  __syncthreads();

  const int oc = t & 63, jw = t >> 6;
  const int h2 = oc / 5, c5 = oc - h2 * 5;
  const int c8b = c5 * 8;
  float acc2[8];
#pragma unroll
  for (int c = 0; c < 8; c++) acc2[c] = 0.f;

  if (oc < 60) {
    const int vbase = (c8b < 16) ? (h2 * 16 + c8b) : (192 + h2 * 24 + (c8b - 16));
    for (int ch = 0; ch < 16; ch++) {
      const int j0c = jw * 64 + ch * 4;
      const float4 p4 = *reinterpret_cast<const float4*>(&aL[aidx(h2, j0c)]);
#pragma unroll
      for (int jj = 0; jj < 4; jj++) {
        const float* vr = &vcat[(size_t)(j0c + jj) * 480 + vbase];
        const float4 va = *reinterpret_cast<const float4*>(vr);
        const float4 vb = *reinterpret_cast<const float4*>(vr + 4);
        const float pv = f4c(p4, jj);
        acc2[0] += pv * va.x; acc2[1] += pv * va.y;
        acc2[2] += pv * va.z; acc2[3] += pv * va.w;
        acc2[4] += pv * vb.x; acc2[5] += pv * vb.y;
        acc2[6] += pv * vb.z; acc2[7] += pv * vb.w;
      }
    }
  }
  if (oc < 60) {
    *reinterpret_cast<float4*>(&red2[((size_t)jw * 64 + oc) * 8]) =
      make_float4(acc2[0], acc2[1], acc2[2], acc2[3]);
    *reinterpret_cast<float4*>(&red2[((size_t)jw * 64 + oc) * 8 + 4]) =
      make_float4(acc2[4], acc2[5], acc2[6], acc2[7]);
  }
  __syncthreads();

  for (int e = t; e < 480; e += 512) {
    const int oc2 = e >> 3, cc = e & 7;
    float sv = 0.f;
#pragma unroll
    for (int w2 = 0; w2 < 8; w2++) sv += red2[((size_t)w2 * 64 + oc2) * 8 + cc];
    const int hh = e / 40, c40 = e - hh * 40;
    if (c40 < 16) cat[(size_t)i * CATd + hh * 16 + c40] = sv;
    else optF[hh * 24 + (c40 - 16)] = sv;
  }
  __syncthreads();

  if (t < 96) {
    const int h = t >> 3, p = t & 7;
    const float* Rm = rot + i * 9;
    const float* tr = trans + i * 3;
    float ox = optF[h * 24 + p * 3 + 0] - tr[0];
    float oy = optF[h * 24 + p * 3 + 1] - tr[1];
    float oz = optF[h * 24 + p * 3 + 2] - tr[2];
    float rx = Rm[0] * ox + Rm[3] * oy + Rm[6] * oz;
    float ry = Rm[1] * ox + Rm[4] * oy + Rm[7] * oz;
    float rz = Rm[2] * ox + Rm[5] * oy + Rm[8] * oz;
    float nrm = sqrtf(rx * rx + ry * ry + rz * rz + 1e-8f);
    size_t b = (size_t)i * CATd;
    cat[b + 192 + t] = rx; cat[b + 288 + t] = ry;
    cat[b + 384 + t] = rz; cat[b + 480 + t] = nrm;
  }
}

// ---------------- Kernel 5: split-K GEMM out = cat @ w_out ----------------
__global__ void k_final(const float* __restrict__ cat, const float* __restrict__ w_out,
                        float* __restrict__ part)
{
  __shared__ float sT[KF_CHUNK * 36];
  const int t  = threadIdx.x;
  const int i0 = blockIdx.x * 32;
  const int c0 = blockIdx.y * 64;
  const int k0 = blockIdx.z * KF_CHUNK;

  for (int u = t; u < 32 * KF_CHUNK; u += 256) {
    int row = u / KF_CHUNK, kk = u % KF_CHUNK;
    sT[kk * 36 + row] = cat[(size_t)(i0 + row) * CATd + k0 + kk];
  }
  __syncthreads();

  const int c    = t & 63;
  const int rgrp = t >> 6;
  const int r0   = rgrp * 8;
  const int gc   = c0 + c;

  float acc[8];
#pragma unroll
  for (int j = 0; j < 8; j++) acc[j] = 0.f;

  const float* wp = w_out + (size_t)k0 * 384 + gc;
#pragma unroll 4
  for (int kk = 0; kk < KF_CHUNK; kk++) {
    float wv = wp[(size_t)kk * 384];
    const float4 a0 = *reinterpret_cast<const float4*>(&sT[kk * 36 + r0]);
    const float4 a1 = *reinterpret_cast<const float4*>(&sT[kk * 36 + r0 + 4]);
    acc[0] += a0.x * wv; acc[1] += a0.y * wv; acc[2] += a0.z * wv; acc[3] += a0.w * wv;
    acc[4] += a1.x * wv; acc[5] += a1.y * wv; acc[6] += a1.z * wv; acc[7] += a1.w * wv;
  }

  float* pb = part + (size_t)blockIdx.z * NN * 384;
#pragma unroll
  for (int j = 0; j < 8; j++)
    pb[(size_t)(i0 + r0 + j) * 384 + gc] = acc[j];
}

// ---------------- Kernel 6: reduce partials + bias ----------------
__global__ void k_reduce(const float* __restrict__ part, const float* __restrict__ b_out,
                         float* __restrict__ out)
{
  const int idx = blockIdx.x * 256 + threadIdx.x;
  const int c = idx % 384;
  float acc = b_out[c];
#pragma unroll
  for (int ks = 0; ks < KF_SPLIT; ks++)
    acc += part[(size_t)ks * NN * 384 + idx];
  out[idx] = acc;
}

extern "C" void kernel_launch(void* const* d_in, const int* in_sizes, int n_in,
                              void* d_out, int out_size, void* d_ws, size_t ws_size,
                              hipStream_t stream) {
  const float* s      = (const float*)d_in[0];
  const float* z      = (const float*)d_in[1];
  const float* rot    = (const float*)d_in[2];
  const float* trans  = (const float*)d_in[3];
  const float* mask   = (const float*)d_in[4];
  const float* w_q    = (const float*)d_in[5];
  const float* b_q    = (const float*)d_in[6];
  const float* w_kv   = (const float*)d_in[7];
  const float* b_kv   = (const float*)d_in[8];
  const float* w_qp   = (const float*)d_in[9];
  const float* b_qp   = (const float*)d_in[10];
  const float* w_kvp  = (const float*)d_in[11];
  const float* b_kvp  = (const float*)d_in[12];
  const float* w_b    = (const float*)d_in[13];
  const float* b_b    = (const float*)d_in[14];
  const float* hws    = (const float*)d_in[15];
  const float* w_out  = (const float*)d_in[16];
  const float* b_out  = (const float*)d_in[17];
  float* out = (float*)d_out;

  float* ws   = (float*)d_ws;
  float* q    = ws;                  // 512*192
  float* kT   = q    + 98304;        // [192][512] j-major
  float* vcat = kT   + 98304;        // [512][480] = [v | vp_rot]
  float* qp   = vcat + 245760;       // 512*144
  float* kpT  = qp   + 73728;        // [144][512] j-major
  float* a    = kpT  + 73728;        // 12*512*512 logits
  float* cat  = a    + 3145728;      // 512*2112
  float* proj = a;                   // alias: consumed before k_logits writes a
  float* part = a;                   // alias: logits dead after k_out

  k_projgemm<<<dim3(16, 18), 256, 0, stream>>>(s, w_q, b_q, w_kv, b_kv,
                                               w_qp, b_qp, w_kvp, b_kvp, proj);
  k_rot<<<512, 256, 0, stream>>>(proj, rot, trans, q, kT, vcat, qp, kpT);
  k_logits<<<1024, 256, 0, stream>>>(z, w_b, b_b, mask, q, kT, qp, kpT, hws, a);
  k_out<<<512, 512, 0, stream>>>(a, vcat, z, rot, trans, cat);
  k_final<<<dim3(16, 6, KF_SPLIT), 256, 0, stream>>>(cat, w_out, part);
  k_reduce<<<768, 256, 0, stream>>>(part, b_out, out);
}

// Round 8
// 201.362 us; speedup vs baseline: 1.2515x; 1.0006x over previous
//
#include <hip/hip_runtime.h>
#include <math.h>

#define NN 512
#define CSd 384
#define CATd 2112
#define KF_CHUNK 264
#define KF_SPLIT 8

// padded logits-tile index: 12 rows, each row = 8 sub-blocks of 64 j padded to 68
__device__ __forceinline__ int aidx(int h, int j) {
  return h * 544 + ((j >> 6) * 68) + (j & 63);
}
__device__ __forceinline__ float f4c(const float4& v, int k) {
  return k == 0 ? v.x : (k == 1 ? v.y : (k == 2 ? v.z : v.w));
}

// ---------------- Kernel 1a: fused projection GEMM ----------------
__global__ void k_projgemm(const float* __restrict__ s,
                           const float* __restrict__ w_q, const float* __restrict__ b_q,
                           const float* __restrict__ w_kv, const float* __restrict__ b_kv,
                           const float* __restrict__ w_qp, const float* __restrict__ b_qp,
                           const float* __restrict__ w_kvp, const float* __restrict__ b_kvp,
                           float* __restrict__ proj)
{
  __shared__ float sT[384 * 40];
  const int t  = threadIdx.x;
  const int i0 = blockIdx.x * 32;
  const int c0 = blockIdx.y * 64;

  for (int u = t; u < 32 * 384; u += 256) {
    int row = u / 384, col = u % 384;
    sT[col * 40 + row] = s[(i0 + row) * CSd + col];
  }
  __syncthreads();

  const int c    = t & 63;
  const int rgrp = t >> 6;
  const int gc   = c0 + c;

  const float* wp;
  int stride;
  float bias;
  if (gc < 192)      { wp = w_q   + gc;         stride = 192; bias = b_q[gc]; }
  else if (gc < 576) { wp = w_kv  + (gc - 192); stride = 384; bias = b_kv[gc - 192]; }
  else if (gc < 720) { wp = w_qp  + (gc - 576); stride = 144; bias = b_qp[gc - 576]; }
  else               { wp = w_kvp + (gc - 720); stride = 432; bias = b_kvp[gc - 720]; }

  float acc[8];
#pragma unroll
  for (int j = 0; j < 8; j++) acc[j] = bias;

  const int r0 = rgrp * 8;
#pragma unroll 4
  for (int kk = 0; kk < 384; kk++) {
    float wv = *wp; wp += stride;
    const float4 a0 = *reinterpret_cast<const float4*>(&sT[kk * 40 + r0]);
    const float4 a1 = *reinterpret_cast<const float4*>(&sT[kk * 40 + r0 + 4]);
    acc[0] += a0.x * wv; acc[1] += a0.y * wv; acc[2] += a0.z * wv; acc[3] += a0.w * wv;
    acc[4] += a1.x * wv; acc[5] += a1.y * wv; acc[6] += a1.z * wv; acc[7] += a1.w * wv;
  }
#pragma unroll
  for (int j = 0; j < 8; j++)
    proj[(size_t)(i0 + r0 + j) * 1152 + gc] = acc[j];
}

// ---------------- Kernel 1b: scatter q/kT/vcat + rotate points ----------------
__global__ void k_rot(const float* __restrict__ proj,
                      const float* __restrict__ rot, const float* __restrict__ trans,
                      float* __restrict__ q, float* __restrict__ kT, float* __restrict__ vcat,
                      float* __restrict__ qp, float* __restrict__ kpT)
{
  __shared__ float ptsL[576];
  const int i = blockIdx.x, t = threadIdx.x;
  const float* pr = proj + (size_t)i * 1152;

  for (int u = t; u < 576; u += 256) ptsL[u] = pr[576 + u];

  for (int cI = t; cI < 576; cI += 256) {
    float pv = pr[cI];
    if (cI < 192) q[i * 192 + cI] = pv;
    else {
      int local = cI - 192, h = local >> 5, cc = local & 31;
      if (cc < 16) kT[(size_t)(h * 16 + cc) * NN + i] = pv;
      else         vcat[(size_t)i * 480 + h * 16 + (cc - 16)] = pv;
    }
  }
  __syncthreads();

  for (int p = t; p < 192; p += 256) {
    float x, y, zz;
    if (p < 48) { x = ptsL[p]; y = ptsL[48 + p]; zz = ptsL[96 + p]; }
    else { int idx = p - 48; x = ptsL[144 + idx]; y = ptsL[288 + idx]; zz = ptsL[432 + idx]; }
    const float* Rm = rot + i * 9;
    const float* tr = trans + i * 3;
    float rx = Rm[0] * x + Rm[1] * y + Rm[2] * zz + tr[0];
    float ry = Rm[3] * x + Rm[4] * y + Rm[5] * zz + tr[1];
    float rz = Rm[6] * x + Rm[7] * y + Rm[8] * zz + tr[2];
    if (p < 48) {
      float* d = qp + ((size_t)i * 48 + p) * 3;
      d[0] = rx; d[1] = ry; d[2] = rz;
    } else {
      int idx = p - 48, h = idx / 12, pp = idx % 12;
      if (pp < 4) {
        size_t rbase = (size_t)((h * 4 + pp) * 3) * NN + i;
        kpT[rbase] = rx; kpT[rbase + NN] = ry; kpT[rbase + 2 * NN] = rz;
      } else {
        size_t rbase = (size_t)i * 480 + 192 + (h * 8 + pp - 4) * 3;
        vcat[rbase] = rx; vcat[rbase + 1] = ry; vcat[rbase + 2] = rz;
      }
    }
  }
}

// ---------------- Kernel 2: logits = z@w_b + qk + pt + mask (reg-direct) ----------------
// grid 1024 (i = b>>1, j-half = b&1), 256 threads; thread owns one (i,j); no LDS.
__global__ void k_logits(const float* __restrict__ z, const float* __restrict__ w_b,
                         const float* __restrict__ b_b, const float* __restrict__ mask,
                         const float* __restrict__ q, const float* __restrict__ kT,
                         const float* __restrict__ qp, const float* __restrict__ kpT,
                         const float* __restrict__ hws,
                         float* __restrict__ a)
{
  const int t = threadIdx.x;
  const int i = blockIdx.x >> 1;
  const int j = ((blockIdx.x & 1) << 8) + t;

  // ---- z @ w_b: stream 128 c in 4 chunks of 8 float4 ----
  float acc[12];
#pragma unroll
  for (int h = 0; h < 12; h++) acc[h] = 0.f;

  const float4* zr = reinterpret_cast<const float4*>(z + ((size_t)i * NN + j) * 128);
#pragma unroll
  for (int ch = 0; ch < 4; ch++) {
    float4 zc[8];
#pragma unroll
    for (int u = 0; u < 8; u++) zc[u] = zr[ch * 8 + u];
#pragma unroll
    for (int u = 0; u < 8; u++) {
      const int c0 = ch * 32 + u * 4;
#pragma unroll
      for (int h = 0; h < 12; h++) {
        // w_b row-major [128][12]; i-uniform-free: these are lane-uniform scalar loads
        acc[h] += zc[u].x * w_b[(c0 + 0) * 12 + h]
                + zc[u].y * w_b[(c0 + 1) * 12 + h]
                + zc[u].z * w_b[(c0 + 2) * 12 + h]
                + zc[u].w * w_b[(c0 + 3) * 12 + h];
      }
    }
  }

  const float mterm = 100000.0f * (mask[i] * mask[j] - 1.0f);
  const float W_L = 0.57735026919f;
  const float W_C = 0.14433756730f;

  // ---- qk + point term, per h; q/qp are block-uniform (scalar-loaded) ----
#pragma unroll
  for (int h = 0; h < 12; h++) {
    float dot = 0.f;
#pragma unroll
    for (int c = 0; c < 16; c++)
      dot += q[i * 192 + h * 16 + c] * kT[(size_t)(h * 16 + c) * NN + j];
    float d2 = 0.f;
#pragma unroll
    for (int pc = 0; pc < 12; pc++) {
      float dd = qp[(size_t)i * 144 + h * 12 + pc] - kpT[(size_t)(h * 12 + pc) * NN + j];
      d2 += dd * dd;
    }
    const float hwv = 0.13608276348f * log1pf(expf(hws[h]));
    a[((size_t)h * NN + i) * NN + j] =
        W_L * (acc[h] + b_b[h]) + mterm + W_C * dot - 0.5f * hwv * d2;
  }
}

// ---------------- Kernel 3: softmax + o + o_pt + o_pair (register-tiled) ----------------
// grid 512 (one per i), 512 threads
__global__ void __launch_bounds__(512, 2)
k_out(const float* __restrict__ a, const float* __restrict__ vcat,
      const float* __restrict__ z,
      const float* __restrict__ rot, const float* __restrict__ trans,
      float* __restrict__ cat)
{
  __shared__ float aL[12 * 544];
  __shared__ float redp[8][16][56];
  __shared__ float optF[288];
  float* red2 = &redp[0][0][0];

  const int i = blockIdx.x, t = threadIdx.x;

  for (int u = t; u < 12 * 512; u += 512) {
    int h = u >> 9, j = u & 511;
    aL[aidx(h, j)] = a[((size_t)h * NN + i) * NN + j];
  }
  __syncthreads();

  {
    const int wv = t >> 6, l = t & 63;
    for (int h = wv; h < 12; h += 8) {
      const int j0 = l * 8;
      float4 x0 = *reinterpret_cast<const float4*>(&aL[aidx(h, j0)]);
      float4 x1 = *reinterpret_cast<const float4*>(&aL[aidx(h, j0 + 4)]);
      float m8 = fmaxf(fmaxf(fmaxf(x0.x, x0.y), fmaxf(x0.z, x0.w)),
                       fmaxf(fmaxf(x1.x, x1.y), fmaxf(x1.z, x1.w)));
      for (int o = 1; o < 64; o <<= 1) m8 = fmaxf(m8, __shfl_xor(m8, o));
      x0.x = expf(x0.x - m8); x0.y = expf(x0.y - m8);
      x0.z = expf(x0.z - m8); x0.w = expf(x0.w - m8);
      x1.x = expf(x1.x - m8); x1.y = expf(x1.y - m8);
      x1.z = expf(x1.z - m8); x1.w = expf(x1.w - m8);
      float s8 = x0.x + x0.y + x0.z + x0.w + x1.x + x1.y + x1.z + x1.w;
      for (int o = 1; o < 64; o <<= 1) s8 += __shfl_xor(s8, o);
      float inv = 1.0f / s8;
      x0.x *= inv; x0.y *= inv; x0.z *= inv; x0.w *= inv;
      x1.x *= inv; x1.y *= inv; x1.z *= inv; x1.w *= inv;
      *reinterpret_cast<float4*>(&aL[aidx(h, j0)]) = x0;
      *reinterpret_cast<float4*>(&aL[aidx(h, j0 + 4)]) = x1;
    }
  }
  __syncthreads();

  const int cg = t & 15;
  const int jq = (t >> 4) & 3;
  const int wv = t >> 6;
  float acc1[12][8];
#pragma unroll
  for (int h = 0; h < 12; h++)
#pragma unroll
    for (int c = 0; c < 8; c++) acc1[h][c] = 0.f;

  {
    const int c8 = cg * 8;
    const int jb = wv * 64 + jq * 16;
    const float* zb = z + (size_t)i * 65536 + c8;
    for (int ch = 0; ch < 4; ch++) {
      const int j0c = jb + ch * 4;
      float4 p4[12];
#pragma unroll
      for (int h = 0; h < 12; h++)
        p4[h] = *reinterpret_cast<const float4*>(&aL[aidx(h, j0c)]);
#pragma unroll
      for (int jj = 0; jj < 4; jj++) {
        const float4 za = *reinterpret_cast<const float4*>(&zb[(size_t)(j0c + jj) * 128]);
        const float4 zc = *reinterpret_cast<const float4*>(&zb[(size_t)(j0c + jj) * 128 + 4]);
#pragma unroll
        for (int h = 0; h < 12; h++) {
          const float pv = f4c(p4[h], jj);
          acc1[h][0] += pv * za.x; acc1[h][1] += pv * za.y;
          acc1[h][2] += pv * za.z; acc1[h][3] += pv * za.w;
          acc1[h][4] += pv * zc.x; acc1[h][5] += pv * zc.y;
          acc1[h][6] += pv * zc.z; acc1[h][7] += pv * zc.w;
        }
      }
    }
#pragma unroll
    for (int h = 0; h < 12; h++)
#pragma unroll
      for (int c = 0; c < 8; c++) {
        float v2 = acc1[h][c];
        v2 += __shfl_xor(v2, 16);
        v2 += __shfl_xor(v2, 32);
        acc1[h][c] = v2;
      }
  }

  if (jq == 0) {
#pragma unroll
    for (int h = 0; h < 6; h++) {
      *reinterpret_cast<float4*>(&redp[wv][cg][h * 8]) =
        make_float4(acc1[h][0], acc1[h][1], acc1[h][2], acc1[h][3]);
      *reinterpret_cast<float4*>(&redp[wv][cg][h * 8 + 4]) =
        make_float4(acc1[h][4], acc1[h][5], acc1[h][6], acc1[h][7]);
    }
  }
  __syncthreads();
  for (int e = t; e < 768; e += 512) {
    int h = e >> 7, c = e & 127;
    float sv = 0.f;
#pragma unroll
    for (int w2 = 0; w2 < 8; w2++) sv += redp[w2][c >> 3][h * 8 + (c & 7)];
    cat[(size_t)i * CATd + 576 + e] = sv;
  }
  __syncthreads();

  if (jq == 0) {
#pragma unroll
    for (int h = 0; h < 6; h++) {
      *reinterpret_cast<float4*>(&redp[wv][cg][h * 8]) =
        make_float4(acc1[6 + h][0], acc1[6 + h][1], acc1[6 + h][2], acc1[6 + h][3]);
      *reinterpret_cast<float4*>(&redp[wv][cg][h * 8 + 4]) =
        make_float4(acc1[6 + h][4], acc1[6 + h][5], acc1[6 + h][6], acc1[6 + h][7]);
    }
  }
  __syncthreads();
  for (int e = t; e < 768; e += 512) {
    int h = e >> 7, c = e & 127;
    float sv = 0.f;
#pragma unroll
    for (int w2 = 0; w2 < 8; w2++) sv += redp[w2][c >> 3][h * 8 + (c & 7)];
    cat[(size_t)i * CATd + 576 + 768 + e] = sv;
  }
  __syncthreads();

  const int oc = t & 63, jw = t >> 6;
  const int h2 = oc / 5, c5 = oc - h2 * 5;
  const int c8b = c5 * 8;
  float acc2[8];
#pragma unroll
  for (int c = 0; c < 8; c++) acc2[c] = 0.f;

  if (oc < 60) {
    const int vbase = (c8b < 16) ? (h2 * 16 + c8b) : (192 + h2 * 24 + (c8b - 16));
    for (int ch = 0; ch < 16; ch++) {
      const int j0c = jw * 64 + ch * 4;
      const float4 p4 = *reinterpret_cast<const float4*>(&aL[aidx(h2, j0c)]);
#pragma unroll
      for (int jj = 0; jj < 4; jj++) {
        const float* vr = &vcat[(size_t)(j0c + jj) * 480 + vbase];
        const float4 va = *reinterpret_cast<const float4*>(vr);
        const float4 vb = *reinterpret_cast<const float4*>(vr + 4);
        const float pv = f4c(p4, jj);
        acc2[0] += pv * va.x; acc2[1] += pv * va.y;
        acc2[2] += pv * va.z; acc2[3] += pv * va.w;
        acc2[4] += pv * vb.x; acc2[5] += pv * vb.y;
        acc2[6] += pv * vb.z; acc2[7] += pv * vb.w;
      }
    }
  }
  if (oc < 60) {
    *reinterpret_cast<float4*>(&red2[((size_t)jw * 64 + oc) * 8]) =
      make_float4(acc2[0], acc2[1], acc2[2], acc2[3]);
    *reinterpret_cast<float4*>(&red2[((size_t)jw * 64 + oc) * 8 + 4]) =
      make_float4(acc2[4], acc2[5], acc2[6], acc2[7]);
  }
  __syncthreads();

  for (int e = t; e < 480; e += 512) {
    const int oc2 = e >> 3, cc = e & 7;
    float sv = 0.f;
#pragma unroll
    for (int w2 = 0; w2 < 8; w2++) sv += red2[((size_t)w2 * 64 + oc2) * 8 + cc];
    const int hh = e / 40, c40 = e - hh * 40;
    if (c40 < 16) cat[(size_t)i * CATd + hh * 16 + c40] = sv;
    else optF[hh * 24 + (c40 - 16)] = sv;
  }
  __syncthreads();

  if (t < 96) {
    const int h = t >> 3, p = t & 7;
    const float* Rm = rot + i * 9;
    const float* tr = trans + i * 3;
    float ox = optF[h * 24 + p * 3 + 0] - tr[0];
    float oy = optF[h * 24 + p * 3 + 1] - tr[1];
    float oz = optF[h * 24 + p * 3 + 2] - tr[2];
    float rx = Rm[0] * ox + Rm[3] * oy + Rm[6] * oz;
    float ry = Rm[1] * ox + Rm[4] * oy + Rm[7] * oz;
    float rz = Rm[2] * ox + Rm[5] * oy + Rm[8] * oz;
    float nrm = sqrtf(rx * rx + ry * ry + rz * rz + 1e-8f);
    size_t b = (size_t)i * CATd;
    cat[b + 192 + t] = rx; cat[b + 288 + t] = ry;
    cat[b + 384 + t] = rz; cat[b + 480 + t] = nrm;
  }
}

// ---------------- Kernel 5: split-K GEMM out = cat @ w_out ----------------
__global__ void k_final(const float* __restrict__ cat, const float* __restrict__ w_out,
                        float* __restrict__ part)
{
  __shared__ float sT[KF_CHUNK * 36];
  const int t  = threadIdx.x;
  const int i0 = blockIdx.x * 32;
  const int c0 = blockIdx.y * 64;
  const int k0 = blockIdx.z * KF_CHUNK;

  for (int u = t; u < 32 * KF_CHUNK; u += 256) {
    int row = u / KF_CHUNK, kk = u % KF_CHUNK;
    sT[kk * 36 + row] = cat[(size_t)(i0 + row) * CATd + k0 + kk];
  }
  __syncthreads();

  const int c    = t & 63;
  const int rgrp = t >> 6;
  const int r0   = rgrp * 8;
  const int gc   = c0 + c;

  float acc[8];
#pragma unroll
  for (int j = 0; j < 8; j++) acc[j] = 0.f;

  const float* wp = w_out + (size_t)k0 * 384 + gc;
#pragma unroll 4
  for (int kk = 0; kk < KF_CHUNK; kk++) {
    float wv = wp[(size_t)kk * 384];
    const float4 a0 = *reinterpret_cast<const float4*>(&sT[kk * 36 + r0]);
    const float4 a1 = *reinterpret_cast<const float4*>(&sT[kk * 36 + r0 + 4]);
    acc[0] += a0.x * wv; acc[1] += a0.y * wv; acc[2] += a0.z * wv; acc[3] += a0.w * wv;
    acc[4] += a1.x * wv; acc[5] += a1.y * wv; acc[6] += a1.z * wv; acc[7] += a1.w * wv;
  }

  float* pb = part + (size_t)blockIdx.z * NN * 384;
#pragma unroll
  for (int j = 0; j < 8; j++)
    pb[(size_t)(i0 + r0 + j) * 384 + gc] = acc[j];
}

// ---------------- Kernel 6: reduce partials + bias ----------------
__global__ void k_reduce(const float* __restrict__ part, const float* __restrict__ b_out,
                         float* __restrict__ out)
{
  const int idx = blockIdx.x * 256 + threadIdx.x;
  const int c = idx % 384;
  float acc = b_out[c];
#pragma unroll
  for (int ks = 0; ks < KF_SPLIT; ks++)
    acc += part[(size_t)ks * NN * 384 + idx];
  out[idx] = acc;
}

extern "C" void kernel_launch(void* const* d_in, const int* in_sizes, int n_in,
                              void* d_out, int out_size, void* d_ws, size_t ws_size,
                              hipStream_t stream) {
  const float* s      = (const float*)d_in[0];
  const float* z      = (const float*)d_in[1];
  const float* rot    = (const float*)d_in[2];
  const float* trans  = (const float*)d_in[3];
  const float* mask   = (const float*)d_in[4];
  const float* w_q    = (const float*)d_in[5];
  const float* b_q    = (const float*)d_in[6];
  const float* w_kv   = (const float*)d_in[7];
  const float* b_kv   = (const float*)d_in[8];
  const float* w_qp   = (const float*)d_in[9];
  const float* b_qp   = (const float*)d_in[10];
  const float* w_kvp  = (const float*)d_in[11];
  const float* b_kvp  = (const float*)d_in[12];
  const float* w_b    = (const float*)d_in[13];
  const float* b_b    = (const float*)d_in[14];
  const float* hws    = (const float*)d_in[15];
  const float* w_out  = (const float*)d_in[16];
  const float* b_out  = (const float*)d_in[17];
  float* out = (float*)d_out;

  float* ws   = (float*)d_ws;
  float* q    = ws;                  // 512*192
  float* kT   = q    + 98304;        // [192][512] j-major
  float* vcat = kT   + 98304;        // [512][480] = [v | vp_rot]
  float* qp   = vcat + 245760;       // 512*144
  float* kpT  = qp   + 73728;        // [144][512] j-major
  float* a    = kpT  + 73728;        // 12*512*512 logits
  float* cat  = a    + 3145728;      // 512*2112
  float* proj = a;                   // alias: consumed before k_logits writes a
  float* part = a;                   // alias: logits dead after k_out

  k_projgemm<<<dim3(16, 18), 256, 0, stream>>>(s, w_q, b_q, w_kv, b_kv,
                                               w_qp, b_qp, w_kvp, b_kvp, proj);
  k_rot<<<512, 256, 0, stream>>>(proj, rot, trans, q, kT, vcat, qp, kpT);
  k_logits<<<1024, 256, 0, stream>>>(z, w_b, b_b, mask, q, kT, qp, kpT, hws, a);
  k_out<<<512, 512, 0, stream>>>(a, vcat, z, rot, trans, cat);
  k_final<<<dim3(16, 6, KF_SPLIT), 256, 0, stream>>>(cat, w_out, part);
  k_reduce<<<768, 256, 0, stream>>>(part, b_out, out);
}

// Round 9
// 196.638 us; speedup vs baseline: 1.2815x; 1.0240x over previous
//
#include <hip/hip_runtime.h>
#include <math.h>

#define NN 512
#define CSd 384
#define CATd 2112
#define KF_CHUNK 264
#define KF_SPLIT 8

// ---------------- Kernel 1a: fused projection GEMM ----------------
__global__ void k_projgemm(const float* __restrict__ s,
                           const float* __restrict__ w_q, const float* __restrict__ b_q,
                           const float* __restrict__ w_kv, const float* __restrict__ b_kv,
                           const float* __restrict__ w_qp, const float* __restrict__ b_qp,
                           const float* __restrict__ w_kvp, const float* __restrict__ b_kvp,
                           float* __restrict__ proj)
{
  __shared__ float sT[384 * 40];
  const int t  = threadIdx.x;
  const int i0 = blockIdx.x * 32;
  const int c0 = blockIdx.y * 64;

  for (int u = t; u < 32 * 384; u += 256) {
    int row = u / 384, col = u % 384;
    sT[col * 40 + row] = s[(i0 + row) * CSd + col];
  }
  __syncthreads();

  const int c    = t & 63;
  const int rgrp = t >> 6;
  const int gc   = c0 + c;

  const float* wp;
  int stride;
  float bias;
  if (gc < 192)      { wp = w_q   + gc;         stride = 192; bias = b_q[gc]; }
  else if (gc < 576) { wp = w_kv  + (gc - 192); stride = 384; bias = b_kv[gc - 192]; }
  else if (gc < 720) { wp = w_qp  + (gc - 576); stride = 144; bias = b_qp[gc - 576]; }
  else               { wp = w_kvp + (gc - 720); stride = 432; bias = b_kvp[gc - 720]; }

  float acc[8];
#pragma unroll
  for (int j = 0; j < 8; j++) acc[j] = bias;

  const int r0 = rgrp * 8;
#pragma unroll 4
  for (int kk = 0; kk < 384; kk++) {
    float wv = *wp; wp += stride;
    const float4 a0 = *reinterpret_cast<const float4*>(&sT[kk * 40 + r0]);
    const float4 a1 = *reinterpret_cast<const float4*>(&sT[kk * 40 + r0 + 4]);
    acc[0] += a0.x * wv; acc[1] += a0.y * wv; acc[2] += a0.z * wv; acc[3] += a0.w * wv;
    acc[4] += a1.x * wv; acc[5] += a1.y * wv; acc[6] += a1.z * wv; acc[7] += a1.w * wv;
  }
#pragma unroll
  for (int j = 0; j < 8; j++)
    proj[(size_t)(i0 + r0 + j) * 1152 + gc] = acc[j];
}

// ---------------- Kernel 1b: scatter q/kT/vcatT + rotate points ----------------
__global__ void k_rot(const float* __restrict__ proj,
                      const float* __restrict__ rot, const float* __restrict__ trans,
                      float* __restrict__ q, float* __restrict__ kT, float* __restrict__ vcatT,
                      float* __restrict__ qp, float* __restrict__ kpT)
{
  __shared__ float ptsL[576];
  const int i = blockIdx.x, t = threadIdx.x;
  const float* pr = proj + (size_t)i * 1152;

  for (int u = t; u < 576; u += 256) ptsL[u] = pr[576 + u];

  for (int cI = t; cI < 576; cI += 256) {
    float pv = pr[cI];
    if (cI < 192) q[i * 192 + cI] = pv;
    else {
      int local = cI - 192, h = local >> 5, cc = local & 31;
      if (cc < 16) kT[(size_t)(h * 16 + cc) * NN + i] = pv;
      else         vcatT[(size_t)(h * 16 + (cc - 16)) * NN + i] = pv;   // j-major
    }
  }
  __syncthreads();

  for (int p = t; p < 192; p += 256) {
    float x, y, zz;
    if (p < 48) { x = ptsL[p]; y = ptsL[48 + p]; zz = ptsL[96 + p]; }
    else { int idx = p - 48; x = ptsL[144 + idx]; y = ptsL[288 + idx]; zz = ptsL[432 + idx]; }
    const float* Rm = rot + i * 9;
    const float* tr = trans + i * 3;
    float rx = Rm[0] * x + Rm[1] * y + Rm[2] * zz + tr[0];
    float ry = Rm[3] * x + Rm[4] * y + Rm[5] * zz + tr[1];
    float rz = Rm[6] * x + Rm[7] * y + Rm[8] * zz + tr[2];
    if (p < 48) {
      float* d = qp + ((size_t)i * 48 + p) * 3;
      d[0] = rx; d[1] = ry; d[2] = rz;
    } else {
      int idx = p - 48, h = idx / 12, pp = idx % 12;
      if (pp < 4) {
        size_t rbase = (size_t)((h * 4 + pp) * 3) * NN + i;
        kpT[rbase] = rx; kpT[rbase + NN] = ry; kpT[rbase + 2 * NN] = rz;
      } else {
        // o_pt col = 192 + (h*8 + pp-4)*3 + x, j-major
        size_t rbase = (size_t)(192 + (h * 8 + pp - 4) * 3) * NN + i;
        vcatT[rbase] = rx; vcatT[rbase + NN] = ry; vcatT[rbase + 2 * NN] = rz;
      }
    }
  }
}

// ---------------- Kernel 2: logits = z@w_b + qk + pt + mask (reg-direct) ----------------
__global__ void k_logits(const float* __restrict__ z, const float* __restrict__ w_b,
                         const float* __restrict__ b_b, const float* __restrict__ mask,
                         const float* __restrict__ q, const float* __restrict__ kT,
                         const float* __restrict__ qp, const float* __restrict__ kpT,
                         const float* __restrict__ hws,
                         float* __restrict__ a)
{
  const int t = threadIdx.x;
  const int i = blockIdx.x >> 1;
  const int j = ((blockIdx.x & 1) << 8) + t;

  float acc[12];
#pragma unroll
  for (int h = 0; h < 12; h++) acc[h] = 0.f;

  const float4* zr = reinterpret_cast<const float4*>(z + ((size_t)i * NN + j) * 128);
#pragma unroll
  for (int ch = 0; ch < 4; ch++) {
    float4 zc[8];
#pragma unroll
    for (int u = 0; u < 8; u++) zc[u] = zr[ch * 8 + u];
#pragma unroll
    for (int u = 0; u < 8; u++) {
      const int c0 = ch * 32 + u * 4;
#pragma unroll
      for (int h = 0; h < 12; h++) {
        acc[h] += zc[u].x * w_b[(c0 + 0) * 12 + h]
                + zc[u].y * w_b[(c0 + 1) * 12 + h]
                + zc[u].z * w_b[(c0 + 2) * 12 + h]
                + zc[u].w * w_b[(c0 + 3) * 12 + h];
      }
    }
  }

  const float mterm = 100000.0f * (mask[i] * mask[j] - 1.0f);
  const float W_L = 0.57735026919f;
  const float W_C = 0.14433756730f;

#pragma unroll
  for (int h = 0; h < 12; h++) {
    float dot = 0.f;
#pragma unroll
    for (int c = 0; c < 16; c++)
      dot += q[i * 192 + h * 16 + c] * kT[(size_t)(h * 16 + c) * NN + j];
    float d2 = 0.f;
#pragma unroll
    for (int pc = 0; pc < 12; pc++) {
      float dd = qp[(size_t)i * 144 + h * 12 + pc] - kpT[(size_t)(h * 12 + pc) * NN + j];
      d2 += dd * dd;
    }
    const float hwv = 0.13608276348f * log1pf(expf(hws[h]));
    a[((size_t)h * NN + i) * NN + j] =
        W_L * (acc[h] + b_b[h]) + mterm + W_C * dot - 0.5f * hwv * d2;
  }
}

// ---------------- Kernel 3: softmax (P back to a) + o/o_pt + rot/norm ----------------
// grid 512 (one i), 512 threads
__global__ void __launch_bounds__(512)
k_pvt(float* __restrict__ a, const float* __restrict__ vcatT,
      const float* __restrict__ rot, const float* __restrict__ trans,
      float* __restrict__ cat)
{
  __shared__ float PL[12 * 516];   // 24.8 KB
  __shared__ float optF[288];
  const int i = blockIdx.x, t = threadIdx.x;
  const int w = t >> 6, l = t & 63;

  // stage logits (coalesced float4)
  for (int u = t; u < 12 * 128; u += 512) {
    int h = u >> 7, c4 = u & 127;
    *reinterpret_cast<float4*>(&PL[h * 516 + c4 * 4]) =
      *reinterpret_cast<const float4*>(&a[((size_t)h * NN + i) * NN + c4 * 4]);
  }
  __syncthreads();

  // softmax per h-row: wave w owns h = w (+8); lanes stride-64 (conflict-free)
  for (int h = w; h < 12; h += 8) {
    float x[8];
    float m = -1e30f;
#pragma unroll
    for (int k = 0; k < 8; k++) { x[k] = PL[h * 516 + k * 64 + l]; m = fmaxf(m, x[k]); }
    for (int o = 1; o < 64; o <<= 1) m = fmaxf(m, __shfl_xor(m, o));
    float sm = 0.f;
#pragma unroll
    for (int k = 0; k < 8; k++) { x[k] = expf(x[k] - m); sm += x[k]; }
    for (int o = 1; o < 64; o <<= 1) sm += __shfl_xor(sm, o);
    float inv = 1.0f / sm;
#pragma unroll
    for (int k = 0; k < 8; k++) PL[h * 516 + k * 64 + l] = x[k] * inv;
  }
  __syncthreads();

  // write P back for k_opair (coalesced float4)
  for (int u = t; u < 12 * 128; u += 512) {
    int h = u >> 7, c4 = u & 127;
    *reinterpret_cast<float4*>(&a[((size_t)h * NN + i) * NN + c4 * 4]) =
      *reinterpret_cast<const float4*>(&PL[h * 516 + c4 * 4]);
  }

  // o / o_pt: wave-dot-products vs j-major vcatT (coalesced)
  for (int v = w; v < 480; v += 8) {
    const int h = (v < 192) ? (v >> 4) : ((v - 192) / 24);
    const float* vr = vcatT + (size_t)v * NN;
    const float* pr = PL + h * 516;
    float acc = 0.f;
#pragma unroll
    for (int k = 0; k < 8; k++)
      acc += pr[k * 64 + l] * vr[k * 64 + l];
    for (int o = 1; o < 64; o <<= 1) acc += __shfl_xor(acc, o);
    if (l == 0) {
      if (v < 192) cat[(size_t)i * CATd + v] = acc;
      else         optF[v - 192] = acc;
    }
  }
  __syncthreads();

  // inverse rotation + norm
  if (t < 96) {
    const int h = t >> 3, p = t & 7;
    const float* Rm = rot + i * 9;
    const float* tr = trans + i * 3;
    float ox = optF[(h * 8 + p) * 3 + 0] - tr[0];
    float oy = optF[(h * 8 + p) * 3 + 1] - tr[1];
    float oz = optF[(h * 8 + p) * 3 + 2] - tr[2];
    float rx = Rm[0] * ox + Rm[3] * oy + Rm[6] * oz;
    float ry = Rm[1] * ox + Rm[4] * oy + Rm[7] * oz;
    float rz = Rm[2] * ox + Rm[5] * oy + Rm[8] * oz;
    float nrm = sqrtf(rx * rx + ry * ry + rz * rz + 1e-8f);
    size_t b = (size_t)i * CATd;
    cat[b + 192 + t] = rx; cat[b + 288 + t] = ry;
    cat[b + 384 + t] = rz; cat[b + 480 + t] = nrm;
  }
}

// ---------------- Kernel 4: o_pair partials, z streamed coalesced ----------------
// grid (4 j-chunks, 512 i), 256 threads: c2 = t&63 (2 c each), jq = t>>6 (32 j each)
__global__ void k_opair(const float* __restrict__ a, const float* __restrict__ z,
                        float* __restrict__ opart)
{
  __shared__ float PL[12 * 128];       // 6 KB
  __shared__ float red[4][64][26];     // 26.6 KB
  const int jb = blockIdx.x, i = blockIdx.y;
  const int t = threadIdx.x, c2 = t & 63, jq = t >> 6;

  for (int u = t; u < 384; u += 256) {
    int h = u >> 5, c4 = u & 31;
    *reinterpret_cast<float4*>(&PL[h * 128 + c4 * 4]) =
      *reinterpret_cast<const float4*>(&a[((size_t)h * NN + i) * NN + jb * 128 + c4 * 4]);
  }
  __syncthreads();

  float acc[12][2];
#pragma unroll
  for (int h = 0; h < 12; h++) { acc[h][0] = 0.f; acc[h][1] = 0.f; }

  const int j0 = jb * 128 + jq * 32;
  const float2* zr = reinterpret_cast<const float2*>(z + ((size_t)i * NN + j0) * 128) + c2;
  for (int jj = 0; jj < 32; jj++) {
    float2 zv = zr[(size_t)jj * 64];
#pragma unroll
    for (int h = 0; h < 12; h++) {
      float pv = PL[h * 128 + jq * 32 + jj];   // wave-uniform broadcast
      acc[h][0] += pv * zv.x; acc[h][1] += pv * zv.y;
    }
  }

#pragma unroll
  for (int h = 0; h < 12; h++) {
    red[jq][c2][h * 2]     = acc[h][0];
    red[jq][c2][h * 2 + 1] = acc[h][1];
  }
  __syncthreads();

  for (int e = t; e < 1536; e += 256) {
    int h = e >> 7, c = e & 127;
    int ci = c >> 1, half = c & 1;
    float sv = red[0][ci][h * 2 + half] + red[1][ci][h * 2 + half]
             + red[2][ci][h * 2 + half] + red[3][ci][h * 2 + half];
    opart[((size_t)i * 4 + jb) * 1536 + e] = sv;
  }
}

// ---------------- Kernel 5: reduce o_pair partials into cat ----------------
__global__ void k_opreduce(const float* __restrict__ opart, float* __restrict__ cat)
{
  const int idx = blockIdx.x * 256 + threadIdx.x;   // 0 .. 512*1536-1
  const int i = idx / 1536, e = idx - i * 1536;
  const float* pb = opart + (size_t)i * 4 * 1536 + e;
  cat[(size_t)i * CATd + 576 + e] = pb[0] + pb[1536] + pb[3072] + pb[4608];
}

// ---------------- Kernel 6: split-K GEMM out = cat @ w_out ----------------
__global__ void k_final(const float* __restrict__ cat, const float* __restrict__ w_out,
                        float* __restrict__ part)
{
  __shared__ float sT[KF_CHUNK * 36];
  const int t  = threadIdx.x;
  const int i0 = blockIdx.x * 32;
  const int c0 = blockIdx.y * 64;
  const int k0 = blockIdx.z * KF_CHUNK;

  for (int u = t; u < 32 * KF_CHUNK; u += 256) {
    int row = u / KF_CHUNK, kk = u % KF_CHUNK;
    sT[kk * 36 + row] = cat[(size_t)(i0 + row) * CATd + k0 + kk];
  }
  __syncthreads();

  const int c    = t & 63;
  const int rgrp = t >> 6;
  const int r0   = rgrp * 8;
  const int gc   = c0 + c;

  float acc[8];
#pragma unroll
  for (int j = 0; j < 8; j++) acc[j] = 0.f;

  const float* wp = w_out + (size_t)k0 * 384 + gc;
#pragma unroll 4
  for (int kk = 0; kk < KF_CHUNK; kk++) {
    float wv = wp[(size_t)kk * 384];
    const float4 a0 = *reinterpret_cast<const float4*>(&sT[kk * 36 + r0]);
    const float4 a1 = *reinterpret_cast<const float4*>(&sT[kk * 36 + r0 + 4]);
    acc[0] += a0.x * wv; acc[1] += a0.y * wv; acc[2] += a0.z * wv; acc[3] += a0.w * wv;
    acc[4] += a1.x * wv; acc[5] += a1.y * wv; acc[6] += a1.z * wv; acc[7] += a1.w * wv;
  }

  float* pb = part + (size_t)blockIdx.z * NN * 384;
#pragma unroll
  for (int j = 0; j < 8; j++)
    pb[(size_t)(i0 + r0 + j) * 384 + gc] = acc[j];
}

// ---------------- Kernel 7: reduce partials + bias ----------------
__global__ void k_reduce(const float* __restrict__ part, const float* __restrict__ b_out,
                         float* __restrict__ out)
{
  const int idx = blockIdx.x * 256 + threadIdx.x;
  const int c = idx % 384;
  float acc = b_out[c];
#pragma unroll
  for (int ks = 0; ks < KF_SPLIT; ks++)
    acc += part[(size_t)ks * NN * 384 + idx];
  out[idx] = acc;
}

extern "C" void kernel_launch(void* const* d_in, const int* in_sizes, int n_in,
                              void* d_out, int out_size, void* d_ws, size_t ws_size,
                              hipStream_t stream) {
  const float* s      = (const float*)d_in[0];
  const float* z      = (const float*)d_in[1];
  const float* rot    = (const float*)d_in[2];
  const float* trans  = (const float*)d_in[3];
  const float* mask   = (const float*)d_in[4];
  const float* w_q    = (const float*)d_in[5];
  const float* b_q    = (const float*)d_in[6];
  const float* w_kv   = (const float*)d_in[7];
  const float* b_kv   = (const float*)d_in[8];
  const float* w_qp   = (const float*)d_in[9];
  const float* b_qp   = (const float*)d_in[10];
  const float* w_kvp  = (const float*)d_in[11];
  const float* b_kvp  = (const float*)d_in[12];
  const float* w_b    = (const float*)d_in[13];
  const float* b_b    = (const float*)d_in[14];
  const float* hws    = (const float*)d_in[15];
  const float* w_out  = (const float*)d_in[16];
  const float* b_out  = (const float*)d_in[17];
  float* out = (float*)d_out;

  float* ws    = (float*)d_ws;
  float* q     = ws;                   // 512*192
  float* kT    = q     + 98304;        // [192][512]
  float* vcatT = kT    + 98304;        // [480][512] j-major
  float* qp    = vcatT + 245760;       // 512*144
  float* kpT   = qp    + 73728;        // [144][512]
  float* a     = kpT   + 73728;        // 12*512*512 logits -> P
  float* cat   = a     + 3145728;      // 512*2112
  float* opart = cat   + 1081344;      // 512*4*1536 = 3145728
  float* proj  = a;                    // alias: consumed before k_logits writes a
  float* part  = a;                    // alias: P dead after k_opair; k_final later

  k_projgemm<<<dim3(16, 18), 256, 0, stream>>>(s, w_q, b_q, w_kv, b_kv,
                                               w_qp, b_qp, w_kvp, b_kvp, proj);
  k_rot<<<512, 256, 0, stream>>>(proj, rot, trans, q, kT, vcatT, qp, kpT);
  k_logits<<<1024, 256, 0, stream>>>(z, w_b, b_b, mask, q, kT, qp, kpT, hws, a);
  k_pvt<<<512, 512, 0, stream>>>(a, vcatT, rot, trans, cat);
  k_opair<<<dim3(4, 512), 256, 0, stream>>>(a, z, opart);
  k_opreduce<<<3072, 256, 0, stream>>>(opart, cat);
  k_final<<<dim3(16, 6, KF_SPLIT), 256, 0, stream>>>(cat, w_out, part);
  k_reduce<<<768, 256, 0, stream>>>(part, b_out, out);
}